// Round 1
// baseline (489.299 us; speedup 1.0000x reference)
//
#include <hip/hip_runtime.h>
#include <hip/hip_bf16.h>

typedef __bf16 bf16_t;
typedef __bf16 bf16x8 __attribute__((ext_vector_type(8)));
typedef __bf16 bf16x4 __attribute__((ext_vector_type(4)));
typedef float  f32x4  __attribute__((ext_vector_type(4)));

#define DIM   1024
#define NHEAD 16
#define HD    64
#define DFF   4096
#define SEQ   2048
#define NTOK  4096   // B*S

// lgkm-only barrier: drains LDS ops (cross-wave visibility) but leaves
// global->VGPR prefetch loads in flight across the barrier. Implemented
// as inline asm with a "memory" clobber: the builtin intrinsics are
// IntrNoMem and LLVM may reorder LDS ops across them (round-11 postmortem:
// timing-dependent corruption under graph replay = compiler sank a ds op
// across the raw s_barrier). The clobber is a compile-time fence only —
// no hardware vmcnt drain is forced.
__device__ __forceinline__ void lgkm_barrier() {
  asm volatile("s_waitcnt lgkmcnt(0)\n\ts_barrier" ::: "memory");
}

// ------------------------------------------------------------------
// ALL six weight transposes in one launch. 12288 32x32-tile blocks:
//  [0,4096)    wq|wk|wv|wo (DIM x DIM each) -> wqkvT (wo at +3*DIM^2)
//  [4096,8192) w_up  [1024][4096] -> wupT  [4096][1024]
//  [8192,12288) w_down [4096][1024] -> wdownT [1024][4096]
// ------------------------------------------------------------------
struct TP {
  const float *wq, *wk, *wv, *wo, *wup, *wdown;
  bf16_t *wqkvT, *wupT, *wdownT;
};

__global__ __launch_bounds__(256)
void transpose_all(TP tp) {
  __shared__ bf16_t tile[32][33];
  const int id = blockIdx.x;
  const float* src; bf16_t* dst; int M, N, bx, by;
  if (id < 4096) {
    const int w = id >> 10, t = id & 1023;
    src = (w == 0) ? tp.wq : (w == 1) ? tp.wk : (w == 2) ? tp.wv : tp.wo;
    dst = tp.wqkvT + (long)w * DIM * DIM;
    M = DIM; N = DIM; bx = (t & 31) * 32; by = (t >> 5) * 32;
  } else if (id < 8192) {
    const int t = id - 4096;
    src = tp.wup; dst = tp.wupT; M = DIM; N = DFF;
    bx = (t & 127) * 32; by = (t >> 7) * 32;
  } else {
    const int t = id - 8192;
    src = tp.wdown; dst = tp.wdownT; M = DFF; N = DIM;
    bx = (t & 31) * 32; by = (t >> 5) * 32;
  }
  const int tt = threadIdx.x;
  const int r = tt >> 3, c4 = (tt & 7) * 4;
  f32x4 v = *(const f32x4*)&src[(long)(by + r) * N + bx + c4];
  tile[r][c4 + 0] = (bf16_t)v[0]; tile[r][c4 + 1] = (bf16_t)v[1];
  tile[r][c4 + 2] = (bf16_t)v[2]; tile[r][c4 + 3] = (bf16_t)v[3];
  __syncthreads();
  bf16x4 w4;
  w4[0] = tile[c4 + 0][r]; w4[1] = tile[c4 + 1][r];
  w4[2] = tile[c4 + 2][r]; w4[3] = tile[c4 + 3][r];
  *(bf16x4*)&dst[(long)(bx + r) * M + by + c4] = w4;
}

// ------------------------------------------------------------------
// LayerNorm (fp32 in, bf16 out) — ddof=1 std, /(sigma+eps).
// ------------------------------------------------------------------
__global__ __launch_bounds__(256)
void layernorm_k(const float* __restrict__ x, const float* __restrict__ a,
                 const float* __restrict__ b, bf16_t* __restrict__ out) {
  const int row = blockIdx.x;
  const int t   = threadIdx.x;
  const float* xr = x + (long)row * DIM;
  f32x4 v = *(const f32x4*)&xr[t * 4];
  float s1 = v[0] + v[1] + v[2] + v[3];
  float s2 = v[0]*v[0] + v[1]*v[1] + v[2]*v[2] + v[3]*v[3];
  #pragma unroll
  for (int off = 32; off > 0; off >>= 1) {
    s1 += __shfl_down(s1, off);
    s2 += __shfl_down(s2, off);
  }
  __shared__ float r1[4], r2[4];
  if ((t & 63) == 0) { r1[t >> 6] = s1; r2[t >> 6] = s2; }
  __syncthreads();
  s1 = r1[0] + r1[1] + r1[2] + r1[3];
  s2 = r2[0] + r2[1] + r2[2] + r2[3];
  const float mu = s1 * (1.0f / DIM);
  float var = (s2 - (float)DIM * mu * mu) * (1.0f / (DIM - 1));
  var = fmaxf(var, 0.0f);
  const float inv = 1.0f / (sqrtf(var) + 1e-6f);
  f32x4 av = *(const f32x4*)&a[t * 4];
  f32x4 bv = *(const f32x4*)&b[t * 4];
  bf16x4 o;
  o[0] = (bf16_t)(av[0] * (v[0] - mu) * inv + bv[0]);
  o[1] = (bf16_t)(av[1] * (v[1] - mu) * inv + bv[1]);
  o[2] = (bf16_t)(av[2] * (v[2] - mu) * inv + bv[2]);
  o[3] = (bf16_t)(av[3] * (v[3] - mu) * inv + bv[3]);
  *(bf16x4*)&out[(long)row * DIM + t * 4] = o;
}

// Fused: x1b = bf16(x + p0 + p1), h2 = LN2(x1b).  One block per row.
__global__ __launch_bounds__(256)
void reduce_wo_ln(const float* __restrict__ x, const bf16_t* __restrict__ p0,
                  const bf16_t* __restrict__ p1, const float* __restrict__ a,
                  const float* __restrict__ b, bf16_t* __restrict__ x1b,
                  bf16_t* __restrict__ h2) {
  const int row = blockIdx.x;
  const int t   = threadIdx.x;
  const long base = (long)row * DIM + t * 4;
  f32x4 v = *(const f32x4*)&x[base];
  bf16x4 pa = *(const bf16x4*)&p0[base];
  bf16x4 pb = *(const bf16x4*)&p1[base];
  bf16x4 xo;
  xo[0] = (bf16_t)(v[0] + (float)pa[0] + (float)pb[0]);
  xo[1] = (bf16_t)(v[1] + (float)pa[1] + (float)pb[1]);
  xo[2] = (bf16_t)(v[2] + (float)pa[2] + (float)pb[2]);
  xo[3] = (bf16_t)(v[3] + (float)pa[3] + (float)pb[3]);
  *(bf16x4*)&x1b[base] = xo;
  const float w0 = (float)xo[0], w1 = (float)xo[1], w2 = (float)xo[2], w3 = (float)xo[3];
  float s1 = w0 + w1 + w2 + w3;
  float s2 = w0*w0 + w1*w1 + w2*w2 + w3*w3;
  #pragma unroll
  for (int off = 32; off > 0; off >>= 1) {
    s1 += __shfl_down(s1, off);
    s2 += __shfl_down(s2, off);
  }
  __shared__ float r1[4], r2[4];
  if ((t & 63) == 0) { r1[t >> 6] = s1; r2[t >> 6] = s2; }
  __syncthreads();
  s1 = r1[0] + r1[1] + r1[2] + r1[3];
  s2 = r2[0] + r2[1] + r2[2] + r2[3];
  const float mu = s1 * (1.0f / DIM);
  float var = (s2 - (float)DIM * mu * mu) * (1.0f / (DIM - 1));
  var = fmaxf(var, 0.0f);
  const float inv = 1.0f / (sqrtf(var) + 1e-6f);
  f32x4 av = *(const f32x4*)&a[t * 4];
  f32x4 bv = *(const f32x4*)&b[t * 4];
  bf16x4 o;
  o[0] = (bf16_t)(av[0] * (w0 - mu) * inv + bv[0]);
  o[1] = (bf16_t)(av[1] * (w1 - mu) * inv + bv[1]);
  o[2] = (bf16_t)(av[2] * (w2 - mu) * inv + bv[2]);
  o[3] = (bf16_t)(av[3] * (w3 - mu) * inv + bv[3]);
  *(bf16x4*)&h2[(long)row * DIM + t * 4] = o;
}

// attn = (O0 + O1) / (l0 + l1)   (split-KV combine; in-place over O0)
__global__ __launch_bounds__(256)
void combine_att(const bf16_t* __restrict__ O1, const float* __restrict__ l0,
                 const float* __restrict__ l1, bf16_t* __restrict__ O0_attn) {
  const long i = ((long)blockIdx.x * 256 + threadIdx.x) * 4;
  const int n = (int)(i & (DIM - 1));
  const long t = i >> 10;
  const int h = n >> 6;
  const long lidx = ((t >> 11) * NHEAD + h) * SEQ + (t & (SEQ - 1));
  const float inv = 1.0f / (l0[lidx] + l1[lidx]);
  bf16x4 a = *(const bf16x4*)&O0_attn[i];
  bf16x4 b = *(const bf16x4*)&O1[i];
  bf16x4 o;
  o[0] = (bf16_t)(((float)a[0] + (float)b[0]) * inv);
  o[1] = (bf16_t)(((float)a[1] + (float)b[1]) * inv);
  o[2] = (bf16_t)(((float)a[2] + (float)b[2]) * inv);
  o[3] = (bf16_t)(((float)a[3] + (float)b[3]) * inv);
  *(bf16x4*)&O0_attn[i] = o;
}

// out = x1b + bias + p0 + p1  (fp32 out)
__global__ __launch_bounds__(256)
void reduce_fd(const bf16_t* __restrict__ x1b, const float* __restrict__ bias,
               const bf16_t* __restrict__ p0, const bf16_t* __restrict__ p1,
               float* __restrict__ out) {
  const long i = ((long)blockIdx.x * 256 + threadIdx.x) * 4;
  const int n = (int)(i & (DIM - 1));
  bf16x4 xv = *(const bf16x4*)&x1b[i];
  f32x4 bv = *(const f32x4*)&bias[n];
  bf16x4 a = *(const bf16x4*)&p0[i];
  bf16x4 b = *(const bf16x4*)&p1[i];
  f32x4 o;
  o[0] = (float)xv[0] + bv[0] + (float)a[0] + (float)b[0];
  o[1] = (float)xv[1] + bv[1] + (float)a[1] + (float)b[1];
  o[2] = (float)xv[2] + bv[2] + (float)a[2] + (float)b[2];
  o[3] = (float)xv[3] + bv[3] + (float)a[3] + (float)b[3];
  *(f32x4*)&out[i] = o;
}

// ------------------------------------------------------------------
// 128xTBN GEMM v2: reg-prefetch + dbuf LDS + lgkm-only barrier (asm,
// memory-clobbered), PLUS XCD-clustering block swizzle: decode lin with
// y' = lin % gridDim.y FIRST (gridDim.y == 32 == 0 mod 8), so blocks
// sharing an A-tile land on the same XCD under round-robin dispatch.
// blockIdx.z = split-K chunk; EPI_PART -> private partial buffers.
// ------------------------------------------------------------------
enum { EPI_QKV = 1, EPI_BIAS_RELU = 3, EPI_PART = 6 };

#define BM 128
#define BK 32

template <int EPI, int TBN>
__global__ __launch_bounds__(256)
void gemm_bt(const bf16_t* __restrict__ A, int lda,
             const bf16_t* __restrict__ BT, int ldb,
             bf16_t* __restrict__ Cb, bf16_t* __restrict__ Cb2,
             const float* __restrict__ bias,
             int M, int N, int Ks) {
  __shared__ bf16_t sA[2][BM][BK];
  __shared__ bf16_t sB[2][TBN][BK];
  const int tid  = threadIdx.x;
  // XCD-cluster swizzle (bijective remap of the linear block id)
  int lin = blockIdx.x + gridDim.x * (blockIdx.y + gridDim.y * blockIdx.z);
  const int by_ = lin % gridDim.y; lin /= gridDim.y;
  const int bx_ = lin % gridDim.x;
  const int bz_ = lin / gridDim.x;
  const int m0   = by_ * BM;
  const int n0   = bx_ * TBN;
  const long koff = (long)bz_ * Ks;
  const int lane = tid & 63, wave = tid >> 6;
  constexpr int MI = (TBN == 128) ? 4 : 2;
  const int wm = (TBN == 128) ? (wave >> 1) * 64 : wave * 32;
  const int wn = (TBN == 128) ? (wave & 1) * 64 : 0;
  const int fm = lane & 15, fq = lane >> 4;

  const int lr = lane >> 2, lc = (lane & 3) * 8;
  const bf16_t* gA0 = &A[(long)(m0 + wave * 32 + lr) * lda + koff + lc];
  const bf16_t* gA1 = gA0 + 16 * (long)lda;
  const int brow = (TBN == 128) ? wave * 32 : wave * 16;
  const bf16_t* gB0 = &BT[(long)(n0 + brow + lr) * ldb + koff + lc];
  const bf16_t* gB1 = gB0 + 16 * (long)ldb;   // used only when TBN==128

  f32x4 acc[MI][4] = {};
  bf16x8 rA0, rA1, rB0, rB1;

  // prologue: tile 0 -> regs -> buf0; tile 1 -> regs
  rA0 = *(const bf16x8*)gA0;
  rA1 = *(const bf16x8*)gA1;
  rB0 = *(const bf16x8*)gB0;
  if constexpr (TBN == 128) rB1 = *(const bf16x8*)gB1;
  gA0 += BK; gA1 += BK; gB0 += BK; gB1 += BK;
  *(bf16x8*)&sA[0][wave * 32 + lr][lc]      = rA0;
  *(bf16x8*)&sA[0][wave * 32 + 16 + lr][lc] = rA1;
  *(bf16x8*)&sB[0][brow + lr][lc]           = rB0;
  if constexpr (TBN == 128) *(bf16x8*)&sB[0][wave * 32 + 16 + lr][lc] = rB1;
  if (BK < Ks) {
    rA0 = *(const bf16x8*)gA0;
    rA1 = *(const bf16x8*)gA1;
    rB0 = *(const bf16x8*)gB0;
    if constexpr (TBN == 128) rB1 = *(const bf16x8*)gB1;
    gA0 += BK; gA1 += BK; gB0 += BK; gB1 += BK;
  }
  __syncthreads();   // one full sync at start; steady state uses lgkm_barrier

  int p = 0;
  for (int k0 = 0; k0 < Ks; k0 += BK, p ^= 1) {
    if (k0 + BK < Ks) {
      *(bf16x8*)&sA[p ^ 1][wave * 32 + lr][lc]      = rA0;
      *(bf16x8*)&sA[p ^ 1][wave * 32 + 16 + lr][lc] = rA1;
      *(bf16x8*)&sB[p ^ 1][brow + lr][lc]           = rB0;
      if constexpr (TBN == 128) *(bf16x8*)&sB[p ^ 1][wave * 32 + 16 + lr][lc] = rB1;
      if (k0 + 2 * BK < Ks) {
        rA0 = *(const bf16x8*)gA0;
        rA1 = *(const bf16x8*)gA1;
        rB0 = *(const bf16x8*)gB0;
        if constexpr (TBN == 128) rB1 = *(const bf16x8*)gB1;
        gA0 += BK; gA1 += BK; gB0 += BK; gB1 += BK;
      }
    }
    bf16x8 af[MI], bfr[4];
    #pragma unroll
    for (int i = 0; i < MI; i++) af[i]  = *(const bf16x8*)&sA[p][wm + i * 16 + fm][fq * 8];
    #pragma unroll
    for (int j = 0; j < 4; j++)  bfr[j] = *(const bf16x8*)&sB[p][wn + j * 16 + fm][fq * 8];
    #pragma unroll
    for (int i = 0; i < MI; i++)
      #pragma unroll
      for (int j = 0; j < 4; j++)
        acc[i][j] = __builtin_amdgcn_mfma_f32_16x16x32_bf16(af[i], bfr[j], acc[i][j], 0, 0, 0);
    lgkm_barrier();   // drains ds ops only; vm prefetch stays outstanding
  }

  #pragma unroll
  for (int i = 0; i < MI; i++) {
    #pragma unroll
    for (int j = 0; j < 4; j++) {
      const int mb = m0 + wm + i * 16 + fq * 4;
      const int n  = n0 + wn + j * 16 + fm;
      #pragma unroll
      for (int r = 0; r < 4; r++) {
        const int m = mb + r;
        float vv = acc[i][j][r];
        if constexpr (EPI == EPI_QKV) {
          const int mat = n >> 10, h_ = (n >> 6) & 15, d_ = n & 63;
          const int b_ = m >> 11, s_ = m & 2047;
          if (mat == 2) {
            Cb2[((long)(b_ * NHEAD + h_) * HD + d_) * SEQ + s_] = (bf16_t)vv;
          } else {
            Cb[(long)mat * (32L * SEQ * HD) + (((long)(b_ * NHEAD + h_)) * SEQ + s_) * HD + d_] = (bf16_t)vv;
          }
        } else if constexpr (EPI == EPI_BIAS_RELU) {
          Cb[(long)m * N + n] = (bf16_t)fmaxf(vv + bias[n], 0.0f);
        } else {  // EPI_PART
          bf16_t* P = bz_ ? Cb2 : Cb;
          P[(long)m * N + n] = (bf16_t)vv;
        }
      }
    }
  }
}

// ------------------------------------------------------------------
// Flash attention v5: v4 + T14 async-STAGE split.
//  - All per-phase staging addresses (global ptrs + swizzled LDS offsets)
//    hoisted out of the KV loop; pointers advance by constant strides.
//  - K/V tile i+1 is reg-prefetched while tile i computes: loop is
//    {compute(LDS) with loads in flight -> barrier -> ds_write regs ->
//     issue next loads -> barrier}. HBM/L2 latency hides under the
//    64-MFMA + softmax compute phase instead of being serially exposed
//    between back-to-back barriers each iteration.
//  - Q prescale folds log2(e): scores feed v_exp_f32 (exp2) directly,
//    dropping one v_mul per score element.
//  - __launch_bounds__(256,4) pins VGPR<=128 so all 4 blocks/CU stay
//    resident (grid is exactly 4 blocks/CU; LDS 32KB allows 5).
// ------------------------------------------------------------------
#define KVT 128

__device__ __forceinline__ int swz(int grp, int slot) {
  return (grp * 64 + (slot ^ ((slot >> 3) & 7) ^ (grp & 1))) * 8;
}

__global__ __launch_bounds__(256, 4)
void flash_attn(const bf16_t* __restrict__ q, const bf16_t* __restrict__ k,
                const bf16_t* __restrict__ vt,
                bf16_t* __restrict__ O0, bf16_t* __restrict__ O1,
                float* __restrict__ l0, float* __restrict__ l1) {
  __shared__ bf16_t sK[16 * 64 * 8];   // 16 KB
  __shared__ bf16_t sV[16 * 64 * 8];   // 16 KB

  const int tid  = threadIdx.x;
  const int bh   = blockIdx.x & 31, qb = blockIdx.x >> 5;   // XCD-cluster
  const int b    = bh >> 4, h = bh & 15;
  const int lane = tid & 63, wave = tid >> 6;
  const int fm   = lane & 15, fq = lane >> 4;
  const int qw0  = qb * 128 + wave * 32;
  const int kvbase = blockIdx.y * (SEQ / 2);
  bf16_t* Op = blockIdx.y ? O1 : O0;
  float*  lp = blockIdx.y ? l1 : l0;

  const bf16_t* qh  = q  + (long)bh * SEQ * HD;
  const bf16_t* kh  = k  + (long)bh * SEQ * HD;
  const bf16_t* vth = vt + (long)bh * HD * SEQ;

  // Q fragments, prescaled by (1/8)*log2(e) so scores feed exp2 directly
  bf16x8 bQ[2][2];
  #pragma unroll
  for (int qt = 0; qt < 2; qt++)
    #pragma unroll
    for (int kk = 0; kk < 2; kk++) {
      bf16x8 v = *(const bf16x8*)&qh[(long)(qw0 + qt * 16 + fm) * HD + kk * 32 + fq * 8];
      #pragma unroll
      for (int e = 0; e < 8; e++) v[e] = (bf16_t)((float)v[e] * 0.18033688f);
      bQ[qt][kk] = v;
    }

  // hoisted per-phase staging addresses (loop-invariant except ptr advance)
  const bf16_t* gK[4]; const bf16_t* gV[4];
  int oK[4], oV[4];
  #pragma unroll
  for (int p = 0; p < 4; p++) {
    const int id = tid + p * 256;
    {
      const int rho = id >> 3, c0 = (id & 7) * 8;
      const int u = rho >> 5, w = rho & 31;
      const int h2 = (w >> 2) & 1;
      const int fmw = ((w >> 3) << 2) | (w & 3);
      const int kk = (id >> 2) & 1, fq3 = id & 3;
      gK[p] = &kh[(long)(kvbase + rho) * HD + c0];
      oK[p] = swz((u * 2 + h2) * 2 + kk, fq3 * 16 + fmw);
    }
    {
      const int d = id >> 4, c0 = (id & 15) * 8;
      const int u = c0 >> 5, fq3 = (c0 >> 3) & 3;
      const int jd = d >> 4, fmw = d & 15;
      gV[p] = &vth[(long)d * SEQ + kvbase + c0];
      oV[p] = swz(u * 4 + jd, fq3 * 16 + fmw);
    }
  }

  bf16x8 rK[4], rV[4];
  #pragma unroll
  for (int p = 0; p < 4; p++) {            // tile 0 -> regs
    rK[p] = *(const bf16x8*)gK[p]; gK[p] += KVT * HD;
    rV[p] = *(const bf16x8*)gV[p]; gV[p] += KVT;
  }
  #pragma unroll
  for (int p = 0; p < 4; p++) {            // tile 0 -> LDS
    *(bf16x8*)&sK[oK[p]] = rK[p];
    *(bf16x8*)&sV[oV[p]] = rV[p];
  }
  #pragma unroll
  for (int p = 0; p < 4; p++) {            // tile 1 -> regs (stays in flight)
    rK[p] = *(const bf16x8*)gK[p]; gK[p] += KVT * HD;
    rV[p] = *(const bf16x8*)gV[p]; gV[p] += KVT;
  }
  __syncthreads();

  float la = 0.f, lb = 0.f;
  f32x4 oA[4] = {}, oB[4] = {};
  constexpr int NIT = (SEQ / 2) / KVT;

  for (int it = 0; it < NIT; it++) {
    #pragma unroll
    for (int u = 0; u < 4; u++) {
      f32x4 stA[2], stB[2];
      #pragma unroll
      for (int h2 = 0; h2 < 2; h2++) {
        bf16x8 aK0 = *(const bf16x8*)&sK[swz((u * 2 + h2) * 2 + 0, lane)];
        bf16x8 aK1 = *(const bf16x8*)&sK[swz((u * 2 + h2) * 2 + 1, lane)];
        f32x4 z0 = {};
        z0 = __builtin_amdgcn_mfma_f32_16x16x32_bf16(aK0, bQ[0][0], z0, 0, 0, 0);
        stA[h2] = __builtin_amdgcn_mfma_f32_16x16x32_bf16(aK1, bQ[0][1], z0, 0, 0, 0);
        f32x4 z1 = {};
        z1 = __builtin_amdgcn_mfma_f32_16x16x32_bf16(aK0, bQ[1][0], z1, 0, 0, 0);
        stB[h2] = __builtin_amdgcn_mfma_f32_16x16x32_bf16(aK1, bQ[1][1], z1, 0, 0, 0);
      }
      bf16x8 pA, pB;
      #pragma unroll
      for (int h2 = 0; h2 < 2; h2++)
        #pragma unroll
        for (int r = 0; r < 4; r++) {
          const float ea = __builtin_amdgcn_exp2f(stA[h2][r]);
          const float eb = __builtin_amdgcn_exp2f(stB[h2][r]);
          la += ea; lb += eb;
          pA[h2 * 4 + r] = (bf16_t)ea;
          pB[h2 * 4 + r] = (bf16_t)eb;
        }
      #pragma unroll
      for (int jd = 0; jd < 4; jd++) {
        bf16x8 bV = *(const bf16x8*)&sV[swz(u * 4 + jd, lane)];
        oA[jd] = __builtin_amdgcn_mfma_f32_16x16x32_bf16(pA, bV, oA[jd], 0, 0, 0);
        oB[jd] = __builtin_amdgcn_mfma_f32_16x16x32_bf16(pB, bV, oB[jd], 0, 0, 0);
      }
    }
    if (it + 1 < NIT) {
      __syncthreads();                     // all waves done reading tile it
      #pragma unroll
      for (int p = 0; p < 4; p++) {        // tile it+1: regs -> LDS
        *(bf16x8*)&sK[oK[p]] = rK[p];
        *(bf16x8*)&sV[oV[p]] = rV[p];
      }
      if (it + 2 < NIT) {
        #pragma unroll
        for (int p = 0; p < 4; p++) {      // tile it+2 -> regs (in flight)
          rK[p] = *(const bf16x8*)gK[p]; gK[p] += KVT * HD;
          rV[p] = *(const bf16x8*)gV[p]; gV[p] += KVT;
        }
      }
      __syncthreads();                     // tile it+1 visible
    }
  }

  la += __shfl_xor(la, 16); la += __shfl_xor(la, 32);
  lb += __shfl_xor(lb, 16); lb += __shfl_xor(lb, 32);
  if (fq == 0) {
    lp[(long)bh * SEQ + qw0 + fm]      = la;
    lp[(long)bh * SEQ + qw0 + 16 + fm] = lb;
  }

  #pragma unroll
  for (int r = 0; r < 4; r++) {
    const long rowA = ((long)b * SEQ + qw0 + fq * 4 + r) * DIM + h * HD;
    const long rowB = rowA + 16L * DIM;
    #pragma unroll
    for (int jd = 0; jd < 4; jd++) {
      Op[rowA + jd * 16 + fm] = (bf16_t)oA[jd][r];
      Op[rowB + jd * 16 + fm] = (bf16_t)oB[jd][r];
    }
  }
}

// ------------------------------------------------------------------
// ws layout — 65 MB (audited, unchanged from round 10/11):
//  [0,0.5)  l0|l1          dead after combine  -> h2 -> p0_fd
//  [0.5,8.5) wqkvT/woT     dead after QKV/WO   -> h2 -> p0_fd
//  [9,17)   h -> O0 -> attn(in-place) -> ff1
//  [17,25)  qd -> p0_wo -> ff1
//  [25,33)  kd -> p1_wo -> ff1
//  [33,41)  vtd -> ff1
//  [41,49)  O1 -> x1b
//  [49,57)  wdownT (early, live to FFN-down)
//  [57,65)  wupT -> p1_fd
// ------------------------------------------------------------------
extern "C" void kernel_launch(void* const* d_in, const int* in_sizes, int n_in,
                              void* d_out, int out_size, void* d_ws, size_t ws_size,
                              hipStream_t stream) {
  (void)in_sizes; (void)n_in; (void)out_size; (void)ws_size;
  const float* x      = (const float*)d_in[0];
  const float* wq     = (const float*)d_in[2];
  const float* wk     = (const float*)d_in[3];
  const float* wv     = (const float*)d_in[4];
  const float* wo     = (const float*)d_in[5];
  const float* w_up   = (const float*)d_in[6];
  const float* b_up   = (const float*)d_in[7];
  const float* w_down = (const float*)d_in[8];
  const float* b_down = (const float*)d_in[9];
  const float* ln1a   = (const float*)d_in[10];
  const float* ln1b   = (const float*)d_in[11];
  const float* ln2a   = (const float*)d_in[12];
  const float* ln2b   = (const float*)d_in[13];

  char* ws = (char*)d_ws;
  const size_t MB = 1ull << 20;
  const size_t KB = 1ull << 10;
  float*  l0     = (float*)(ws);              // 256 KB
  float*  l1     = (float*)(ws + 256 * KB);   // 256 KB
  bf16_t* wqkvT  = (bf16_t*)(ws + 512 * KB);  // 6 MB
  bf16_t* woT    = (bf16_t*)(ws + 512 * KB + 6 * MB);  // 2 MB
  bf16_t* h      = (bf16_t*)(ws + 9 * MB);
  bf16_t* O0     = (bf16_t*)(ws + 9 * MB);
  bf16_t* attn   = (bf16_t*)(ws + 9 * MB);
  bf16_t* qkv    = (bf16_t*)(ws + 17 * MB);
  bf16_t* qd     = (bf16_t*)(ws + 17 * MB);
  bf16_t* kd     = (bf16_t*)(ws + 25 * MB);
  bf16_t* vtd    = (bf16_t*)(ws + 33 * MB);
  bf16_t* O1     = (bf16_t*)(ws + 41 * MB);
  bf16_t* p0_wo  = (bf16_t*)(ws + 17 * MB);
  bf16_t* p1_wo  = (bf16_t*)(ws + 25 * MB);
  bf16_t* x1b    = (bf16_t*)(ws + 41 * MB);
  bf16_t* h2     = (bf16_t*)(ws);
  bf16_t* wdownT = (bf16_t*)(ws + 49 * MB);
  bf16_t* wupT   = (bf16_t*)(ws + 57 * MB);
  bf16_t* ff1    = (bf16_t*)(ws + 9 * MB);
  bf16_t* p0_fd  = (bf16_t*)(ws);
  bf16_t* p1_fd  = (bf16_t*)(ws + 57 * MB);
  float*  outp   = (float*)d_out;

  const dim3 T(256);
  TP tp{wq, wk, wv, wo, w_up, w_down, wqkvT, wupT, wdownT};
  transpose_all<<<dim3(12288), T, 0, stream>>>(tp);

  layernorm_k<<<dim3(4096), T, 0, stream>>>(x, ln1a, ln1b, h);
  gemm_bt<EPI_QKV, 128><<<dim3(24, 32), T, 0, stream>>>(h, DIM, wqkvT, DIM, qkv, vtd,
                                                        nullptr, NTOK, 3072, DIM);
  flash_attn<<<dim3(512, 2), T, 0, stream>>>(qd, kd, vtd, O0, O1, l0, l1);
  combine_att<<<dim3(NTOK * DIM / 1024), T, 0, stream>>>(O1, l0, l1, attn);
  gemm_bt<EPI_PART, 64><<<dim3(16, 32, 2), T, 0, stream>>>(attn, DIM, woT, DIM, p0_wo, p1_wo,
                                                           nullptr, NTOK, DIM, DIM / 2);
  reduce_wo_ln<<<dim3(4096), T, 0, stream>>>(x, p0_wo, p1_wo, ln2a, ln2b, x1b, h2);
  gemm_bt<EPI_BIAS_RELU, 128><<<dim3(32, 32), T, 0, stream>>>(h2, DIM, wupT, DIM, ff1, nullptr,
                                                              b_up, NTOK, DFF, DIM);
  gemm_bt<EPI_PART, 64><<<dim3(16, 32, 2), T, 0, stream>>>(ff1, DFF, wdownT, DFF, p0_fd, p1_fd,
                                                           nullptr, NTOK, DIM, DFF / 2);
  reduce_fd<<<dim3(NTOK * DIM / 1024), T, 0, stream>>>(x1b, b_down, p0_fd, p1_fd, outp);
}

// Round 3
// 391.868 us; speedup vs baseline: 1.2486x; 1.2486x over previous
//
#include <hip/hip_runtime.h>
#include <hip/hip_bf16.h>

typedef __bf16 bf16_t;
typedef __bf16 bf16x8 __attribute__((ext_vector_type(8)));
typedef __bf16 bf16x4 __attribute__((ext_vector_type(4)));
typedef float  f32x4  __attribute__((ext_vector_type(4)));

#define DIM   1024
#define NHEAD 16
#define HD    64
#define DFF   4096
#define SEQ   2048
#define NTOK  4096   // B*S

// lgkm-only barrier: drains LDS ops (cross-wave visibility) but leaves
// global->VGPR prefetch loads in flight across the barrier.
__device__ __forceinline__ void lgkm_barrier() {
  asm volatile("s_waitcnt lgkmcnt(0)\n\ts_barrier" ::: "memory");
}

// ------------------------------------------------------------------
// ALL six weight transposes in one launch. 12288 32x32-tile blocks.
// ------------------------------------------------------------------
struct TP {
  const float *wq, *wk, *wv, *wo, *wup, *wdown;
  bf16_t *wqkvT, *wupT, *wdownT;
};

__global__ __launch_bounds__(256)
void transpose_all(TP tp) {
  __shared__ bf16_t tile[32][33];
  const int id = blockIdx.x;
  const float* src; bf16_t* dst; int M, N, bx, by;
  if (id < 4096) {
    const int w = id >> 10, t = id & 1023;
    src = (w == 0) ? tp.wq : (w == 1) ? tp.wk : (w == 2) ? tp.wv : tp.wo;
    dst = tp.wqkvT + (long)w * DIM * DIM;
    M = DIM; N = DIM; bx = (t & 31) * 32; by = (t >> 5) * 32;
  } else if (id < 8192) {
    const int t = id - 4096;
    src = tp.wup; dst = tp.wupT; M = DIM; N = DFF;
    bx = (t & 127) * 32; by = (t >> 7) * 32;
  } else {
    const int t = id - 8192;
    src = tp.wdown; dst = tp.wdownT; M = DFF; N = DIM;
    bx = (t & 31) * 32; by = (t >> 5) * 32;
  }
  const int tt = threadIdx.x;
  const int r = tt >> 3, c4 = (tt & 7) * 4;
  f32x4 v = *(const f32x4*)&src[(long)(by + r) * N + bx + c4];
  tile[r][c4 + 0] = (bf16_t)v[0]; tile[r][c4 + 1] = (bf16_t)v[1];
  tile[r][c4 + 2] = (bf16_t)v[2]; tile[r][c4 + 3] = (bf16_t)v[3];
  __syncthreads();
  bf16x4 w4;
  w4[0] = tile[c4 + 0][r]; w4[1] = tile[c4 + 1][r];
  w4[2] = tile[c4 + 2][r]; w4[3] = tile[c4 + 3][r];
  *(bf16x4*)&dst[(long)(bx + r) * M + by + c4] = w4;
}

// ------------------------------------------------------------------
// LayerNorm (fp32 in, bf16 out) — ddof=1 std, /(sigma+eps).
// ------------------------------------------------------------------
__global__ __launch_bounds__(256)
void layernorm_k(const float* __restrict__ x, const float* __restrict__ a,
                 const float* __restrict__ b, bf16_t* __restrict__ out) {
  const int row = blockIdx.x;
  const int t   = threadIdx.x;
  const float* xr = x + (long)row * DIM;
  f32x4 v = *(const f32x4*)&xr[t * 4];
  float s1 = v[0] + v[1] + v[2] + v[3];
  float s2 = v[0]*v[0] + v[1]*v[1] + v[2]*v[2] + v[3]*v[3];
  #pragma unroll
  for (int off = 32; off > 0; off >>= 1) {
    s1 += __shfl_down(s1, off);
    s2 += __shfl_down(s2, off);
  }
  __shared__ float r1[4], r2[4];
  if ((t & 63) == 0) { r1[t >> 6] = s1; r2[t >> 6] = s2; }
  __syncthreads();
  s1 = r1[0] + r1[1] + r1[2] + r1[3];
  s2 = r2[0] + r2[1] + r2[2] + r2[3];
  const float mu = s1 * (1.0f / DIM);
  float var = (s2 - (float)DIM * mu * mu) * (1.0f / (DIM - 1));
  var = fmaxf(var, 0.0f);
  const float inv = 1.0f / (sqrtf(var) + 1e-6f);
  f32x4 av = *(const f32x4*)&a[t * 4];
  f32x4 bv = *(const f32x4*)&b[t * 4];
  bf16x4 o;
  o[0] = (bf16_t)(av[0] * (v[0] - mu) * inv + bv[0]);
  o[1] = (bf16_t)(av[1] * (v[1] - mu) * inv + bv[1]);
  o[2] = (bf16_t)(av[2] * (v[2] - mu) * inv + bv[2]);
  o[3] = (bf16_t)(av[3] * (v[3] - mu) * inv + bv[3]);
  *(bf16x4*)&out[(long)row * DIM + t * 4] = o;
}

// Fused: x1b = bf16(x + p0 + p1), h2 = LN2(x1b).  One block per row.
__global__ __launch_bounds__(256)
void reduce_wo_ln(const float* __restrict__ x, const bf16_t* __restrict__ p0,
                  const bf16_t* __restrict__ p1, const float* __restrict__ a,
                  const float* __restrict__ b, bf16_t* __restrict__ x1b,
                  bf16_t* __restrict__ h2) {
  const int row = blockIdx.x;
  const int t   = threadIdx.x;
  const long base = (long)row * DIM + t * 4;
  f32x4 v = *(const f32x4*)&x[base];
  bf16x4 pa = *(const bf16x4*)&p0[base];
  bf16x4 pb = *(const bf16x4*)&p1[base];
  bf16x4 xo;
  xo[0] = (bf16_t)(v[0] + (float)pa[0] + (float)pb[0]);
  xo[1] = (bf16_t)(v[1] + (float)pa[1] + (float)pb[1]);
  xo[2] = (bf16_t)(v[2] + (float)pa[2] + (float)pb[2]);
  xo[3] = (bf16_t)(v[3] + (float)pa[3] + (float)pb[3]);
  *(bf16x4*)&x1b[base] = xo;
  const float w0 = (float)xo[0], w1 = (float)xo[1], w2 = (float)xo[2], w3 = (float)xo[3];
  float s1 = w0 + w1 + w2 + w3;
  float s2 = w0*w0 + w1*w1 + w2*w2 + w3*w3;
  #pragma unroll
  for (int off = 32; off > 0; off >>= 1) {
    s1 += __shfl_down(s1, off);
    s2 += __shfl_down(s2, off);
  }
  __shared__ float r1[4], r2[4];
  if ((t & 63) == 0) { r1[t >> 6] = s1; r2[t >> 6] = s2; }
  __syncthreads();
  s1 = r1[0] + r1[1] + r1[2] + r1[3];
  s2 = r2[0] + r2[1] + r2[2] + r2[3];
  const float mu = s1 * (1.0f / DIM);
  float var = (s2 - (float)DIM * mu * mu) * (1.0f / (DIM - 1));
  var = fmaxf(var, 0.0f);
  const float inv = 1.0f / (sqrtf(var) + 1e-6f);
  f32x4 av = *(const f32x4*)&a[t * 4];
  f32x4 bv = *(const f32x4*)&b[t * 4];
  bf16x4 o;
  o[0] = (bf16_t)(av[0] * (w0 - mu) * inv + bv[0]);
  o[1] = (bf16_t)(av[1] * (w1 - mu) * inv + bv[1]);
  o[2] = (bf16_t)(av[2] * (w2 - mu) * inv + bv[2]);
  o[3] = (bf16_t)(av[3] * (w3 - mu) * inv + bv[3]);
  *(bf16x4*)&h2[(long)row * DIM + t * 4] = o;
}

// attn = (O0 + O1) / (l0 + l1)   (split-KV combine; in-place over O0)
__global__ __launch_bounds__(256)
void combine_att(const bf16_t* __restrict__ O1, const float* __restrict__ l0,
                 const float* __restrict__ l1, bf16_t* __restrict__ O0_attn) {
  const long i = ((long)blockIdx.x * 256 + threadIdx.x) * 4;
  const int n = (int)(i & (DIM - 1));
  const long t = i >> 10;
  const int h = n >> 6;
  const long lidx = ((t >> 11) * NHEAD + h) * SEQ + (t & (SEQ - 1));
  const float inv = 1.0f / (l0[lidx] + l1[lidx]);
  bf16x4 a = *(const bf16x4*)&O0_attn[i];
  bf16x4 b = *(const bf16x4*)&O1[i];
  bf16x4 o;
  o[0] = (bf16_t)(((float)a[0] + (float)b[0]) * inv);
  o[1] = (bf16_t)(((float)a[1] + (float)b[1]) * inv);
  o[2] = (bf16_t)(((float)a[2] + (float)b[2]) * inv);
  o[3] = (bf16_t)(((float)a[3] + (float)b[3]) * inv);
  *(bf16x4*)&O0_attn[i] = o;
}

// out = x1b + bias + p0 + p1  (fp32 out)
__global__ __launch_bounds__(256)
void reduce_fd(const bf16_t* __restrict__ x1b, const float* __restrict__ bias,
               const bf16_t* __restrict__ p0, const bf16_t* __restrict__ p1,
               float* __restrict__ out) {
  const long i = ((long)blockIdx.x * 256 + threadIdx.x) * 4;
  const int n = (int)(i & (DIM - 1));
  bf16x4 xv = *(const bf16x4*)&x1b[i];
  f32x4 bv = *(const f32x4*)&bias[n];
  bf16x4 a = *(const bf16x4*)&p0[i];
  bf16x4 b = *(const bf16x4*)&p1[i];
  f32x4 o;
  o[0] = (float)xv[0] + bv[0] + (float)a[0] + (float)b[0];
  o[1] = (float)xv[1] + bv[1] + (float)a[1] + (float)b[1];
  o[2] = (float)xv[2] + bv[2] + (float)a[2] + (float)b[2];
  o[3] = (float)xv[3] + bv[3] + (float)a[3] + (float)b[3];
  *(f32x4*)&out[i] = o;
}

// ------------------------------------------------------------------
// 128xTBN GEMM v2: reg-prefetch + dbuf LDS + lgkm-only barrier, XCD swizzle.
// ------------------------------------------------------------------
enum { EPI_QKV = 1, EPI_BIAS_RELU = 3, EPI_PART = 6 };

#define BM 128
#define BK 32

template <int EPI, int TBN>
__global__ __launch_bounds__(256)
void gemm_bt(const bf16_t* __restrict__ A, int lda,
             const bf16_t* __restrict__ BT, int ldb,
             bf16_t* __restrict__ Cb, bf16_t* __restrict__ Cb2,
             const float* __restrict__ bias,
             int M, int N, int Ks) {
  __shared__ bf16_t sA[2][BM][BK];
  __shared__ bf16_t sB[2][TBN][BK];
  const int tid  = threadIdx.x;
  int lin = blockIdx.x + gridDim.x * (blockIdx.y + gridDim.y * blockIdx.z);
  const int by_ = lin % gridDim.y; lin /= gridDim.y;
  const int bx_ = lin % gridDim.x;
  const int bz_ = lin / gridDim.x;
  const int m0   = by_ * BM;
  const int n0   = bx_ * TBN;
  const long koff = (long)bz_ * Ks;
  const int lane = tid & 63, wave = tid >> 6;
  constexpr int MI = (TBN == 128) ? 4 : 2;
  const int wm = (TBN == 128) ? (wave >> 1) * 64 : wave * 32;
  const int wn = (TBN == 128) ? (wave & 1) * 64 : 0;
  const int fm = lane & 15, fq = lane >> 4;

  const int lr = lane >> 2, lc = (lane & 3) * 8;
  const bf16_t* gA0 = &A[(long)(m0 + wave * 32 + lr) * lda + koff + lc];
  const bf16_t* gA1 = gA0 + 16 * (long)lda;
  const int brow = (TBN == 128) ? wave * 32 : wave * 16;
  const bf16_t* gB0 = &BT[(long)(n0 + brow + lr) * ldb + koff + lc];
  const bf16_t* gB1 = gB0 + 16 * (long)ldb;   // used only when TBN==128

  f32x4 acc[MI][4] = {};
  bf16x8 rA0, rA1, rB0, rB1;

  rA0 = *(const bf16x8*)gA0;
  rA1 = *(const bf16x8*)gA1;
  rB0 = *(const bf16x8*)gB0;
  if constexpr (TBN == 128) rB1 = *(const bf16x8*)gB1;
  gA0 += BK; gA1 += BK; gB0 += BK; gB1 += BK;
  *(bf16x8*)&sA[0][wave * 32 + lr][lc]      = rA0;
  *(bf16x8*)&sA[0][wave * 32 + 16 + lr][lc] = rA1;
  *(bf16x8*)&sB[0][brow + lr][lc]           = rB0;
  if constexpr (TBN == 128) *(bf16x8*)&sB[0][wave * 32 + 16 + lr][lc] = rB1;
  if (BK < Ks) {
    rA0 = *(const bf16x8*)gA0;
    rA1 = *(const bf16x8*)gA1;
    rB0 = *(const bf16x8*)gB0;
    if constexpr (TBN == 128) rB1 = *(const bf16x8*)gB1;
    gA0 += BK; gA1 += BK; gB0 += BK; gB1 += BK;
  }
  __syncthreads();

  int p = 0;
  for (int k0 = 0; k0 < Ks; k0 += BK, p ^= 1) {
    if (k0 + BK < Ks) {
      *(bf16x8*)&sA[p ^ 1][wave * 32 + lr][lc]      = rA0;
      *(bf16x8*)&sA[p ^ 1][wave * 32 + 16 + lr][lc] = rA1;
      *(bf16x8*)&sB[p ^ 1][brow + lr][lc]           = rB0;
      if constexpr (TBN == 128) *(bf16x8*)&sB[p ^ 1][wave * 32 + 16 + lr][lc] = rB1;
      if (k0 + 2 * BK < Ks) {
        rA0 = *(const bf16x8*)gA0;
        rA1 = *(const bf16x8*)gA1;
        rB0 = *(const bf16x8*)gB0;
        if constexpr (TBN == 128) rB1 = *(const bf16x8*)gB1;
        gA0 += BK; gA1 += BK; gB0 += BK; gB1 += BK;
      }
    }
    bf16x8 af[MI], bfr[4];
    #pragma unroll
    for (int i = 0; i < MI; i++) af[i]  = *(const bf16x8*)&sA[p][wm + i * 16 + fm][fq * 8];
    #pragma unroll
    for (int j = 0; j < 4; j++)  bfr[j] = *(const bf16x8*)&sB[p][wn + j * 16 + fm][fq * 8];
    #pragma unroll
    for (int i = 0; i < MI; i++)
      #pragma unroll
      for (int j = 0; j < 4; j++)
        acc[i][j] = __builtin_amdgcn_mfma_f32_16x16x32_bf16(af[i], bfr[j], acc[i][j], 0, 0, 0);
    lgkm_barrier();
  }

  #pragma unroll
  for (int i = 0; i < MI; i++) {
    #pragma unroll
    for (int j = 0; j < 4; j++) {
      const int mb = m0 + wm + i * 16 + fq * 4;
      const int n  = n0 + wn + j * 16 + fm;
      #pragma unroll
      for (int r = 0; r < 4; r++) {
        const int m = mb + r;
        float vv = acc[i][j][r];
        if constexpr (EPI == EPI_QKV) {
          const int mat = n >> 10, h_ = (n >> 6) & 15, d_ = n & 63;
          const int b_ = m >> 11, s_ = m & 2047;
          if (mat == 2) {
            Cb2[((long)(b_ * NHEAD + h_) * HD + d_) * SEQ + s_] = (bf16_t)vv;
          } else {
            Cb[(long)mat * (32L * SEQ * HD) + (((long)(b_ * NHEAD + h_)) * SEQ + s_) * HD + d_] = (bf16_t)vv;
          }
        } else if constexpr (EPI == EPI_BIAS_RELU) {
          Cb[(long)m * N + n] = (bf16_t)fmaxf(vv + bias[n], 0.0f);
        } else {  // EPI_PART
          bf16_t* P = bz_ ? Cb2 : Cb;
          P[(long)m * N + n] = (bf16_t)vv;
        }
      }
    }
  }
}

// ------------------------------------------------------------------
// Flash attention v6 = round-0 structure (68-VGPR staging, two syncs
// per tile — the known-good 71.5 us shape) + two VALU-only cuts:
//  1. Q prescaled by 0.125*log2(e); scores feed exp2 directly
//     (removes 64 v_mul per lane per iter).
//  2. Row-sums via MFMA against a ones-fragment (permutation-invariant,
//     so the kv-scrambled V layout doesn't matter): removes 128 scalar
//     adds per lane per iter and the epilogue shuffle-reduce; denominator
//     now uses the same bf16-rounded P as the numerator.
// No prefetch arrays, no launch-bounds cap — register pressure stays in
// the round-0 envelope (round-1 postmortem: 145-VGPR live set + cap 128
// => 470 MB of scratch spills).
// ------------------------------------------------------------------
#define KVT 128

__device__ __forceinline__ int swz(int grp, int slot) {
  return (grp * 64 + (slot ^ ((slot >> 3) & 7) ^ (grp & 1))) * 8;
}

__global__ __launch_bounds__(256)
void flash_attn(const bf16_t* __restrict__ q, const bf16_t* __restrict__ k,
                const bf16_t* __restrict__ vt,
                bf16_t* __restrict__ O0, bf16_t* __restrict__ O1,
                float* __restrict__ l0, float* __restrict__ l1) {
  __shared__ bf16_t sK[16 * 64 * 8];   // 16 KB
  __shared__ bf16_t sV[16 * 64 * 8];   // 16 KB

  const int tid  = threadIdx.x;
  const int bh   = blockIdx.x & 31, qb = blockIdx.x >> 5;   // XCD-cluster
  const int b    = bh >> 4, h = bh & 15;
  const int lane = tid & 63, wave = tid >> 6;
  const int fm   = lane & 15, fq = lane >> 4;
  const int qw0  = qb * 128 + wave * 32;
  const int kvbase = blockIdx.y * (SEQ / 2);
  bf16_t* Op = blockIdx.y ? O1 : O0;
  float*  lp = blockIdx.y ? l1 : l0;

  const bf16_t* qh  = q  + (long)bh * SEQ * HD;
  const bf16_t* kh  = k  + (long)bh * SEQ * HD;
  const bf16_t* vth = vt + (long)bh * HD * SEQ;

  // Q prescaled by (1/8)*log2(e): scores feed exp2 directly
  bf16x8 bQ[2][2];
  #pragma unroll
  for (int qt = 0; qt < 2; qt++)
    #pragma unroll
    for (int kk = 0; kk < 2; kk++) {
      bf16x8 v = *(const bf16x8*)&qh[(long)(qw0 + qt * 16 + fm) * HD + kk * 32 + fq * 8];
      #pragma unroll
      for (int e = 0; e < 8; e++) v[e] = (bf16_t)((float)v[e] * 0.18033688f);
      bQ[qt][kk] = v;
    }

  // ones-fragment for MFMA row-sums (permutation-invariant in kv)
  bf16x8 ones;
  #pragma unroll
  for (int e = 0; e < 8; e++) ones[e] = (bf16_t)1.0f;

  f32x4 oA[4] = {}, oB[4] = {};
  f32x4 oLA = {}, oLB = {};

  for (int it = 0; it < (SEQ / 2) / KVT; it++) {
    const int kv0 = kvbase + it * KVT;
    __syncthreads();
    #pragma unroll
    for (int p = 0; p < 4; p++) {
      const int id = tid + p * 256;
      {
        const int rho = id >> 3, c0 = (id & 7) * 8;
        const int u = rho >> 5, w = rho & 31;
        const int h2 = (w >> 2) & 1;
        const int fmw = ((w >> 3) << 2) | (w & 3);
        const int kk = (id >> 2) & 1, fq3 = id & 3;
        bf16x8 g = *(const bf16x8*)&kh[(long)(kv0 + rho) * HD + c0];
        *(bf16x8*)&sK[swz((u * 2 + h2) * 2 + kk, fq3 * 16 + fmw)] = g;
      }
      {
        const int d = id >> 4, c0 = (id & 15) * 8;
        const int u = c0 >> 5, fq3 = (c0 >> 3) & 3;
        const int jd = d >> 4, fmw = d & 15;
        bf16x8 g = *(const bf16x8*)&vth[(long)d * SEQ + kv0 + c0];
        *(bf16x8*)&sV[swz(u * 4 + jd, fq3 * 16 + fmw)] = g;
      }
    }
    __syncthreads();

    #pragma unroll
    for (int u = 0; u < 4; u++) {
      f32x4 stA[2], stB[2];
      #pragma unroll
      for (int h2 = 0; h2 < 2; h2++) {
        bf16x8 aK0 = *(const bf16x8*)&sK[swz((u * 2 + h2) * 2 + 0, lane)];
        bf16x8 aK1 = *(const bf16x8*)&sK[swz((u * 2 + h2) * 2 + 1, lane)];
        f32x4 z0 = {};
        z0 = __builtin_amdgcn_mfma_f32_16x16x32_bf16(aK0, bQ[0][0], z0, 0, 0, 0);
        stA[h2] = __builtin_amdgcn_mfma_f32_16x16x32_bf16(aK1, bQ[0][1], z0, 0, 0, 0);
        f32x4 z1 = {};
        z1 = __builtin_amdgcn_mfma_f32_16x16x32_bf16(aK0, bQ[1][0], z1, 0, 0, 0);
        stB[h2] = __builtin_amdgcn_mfma_f32_16x16x32_bf16(aK1, bQ[1][1], z1, 0, 0, 0);
      }
      bf16x8 pA, pB;
      #pragma unroll
      for (int h2 = 0; h2 < 2; h2++)
        #pragma unroll
        for (int r = 0; r < 4; r++) {
          pA[h2 * 4 + r] = (bf16_t)__builtin_amdgcn_exp2f(stA[h2][r]);
          pB[h2 * 4 + r] = (bf16_t)__builtin_amdgcn_exp2f(stB[h2][r]);
        }
      // row sums on the matrix pipe (replaces 128 scalar adds/iter)
      oLA = __builtin_amdgcn_mfma_f32_16x16x32_bf16(pA, ones, oLA, 0, 0, 0);
      oLB = __builtin_amdgcn_mfma_f32_16x16x32_bf16(pB, ones, oLB, 0, 0, 0);
      #pragma unroll
      for (int jd = 0; jd < 4; jd++) {
        bf16x8 bV = *(const bf16x8*)&sV[swz(u * 4 + jd, lane)];
        oA[jd] = __builtin_amdgcn_mfma_f32_16x16x32_bf16(pA, bV, oA[jd], 0, 0, 0);
        oB[jd] = __builtin_amdgcn_mfma_f32_16x16x32_bf16(pB, bV, oB[jd], 0, 0, 0);
      }
    }
  }

  // oLA/oLB: D[q][c] with all 16 cols equal; lane fm==0 holds q = fq*4+r
  if (fm == 0) {
    #pragma unroll
    for (int r = 0; r < 4; r++) {
      lp[(long)bh * SEQ + qw0 + fq * 4 + r]      = oLA[r];
      lp[(long)bh * SEQ + qw0 + 16 + fq * 4 + r] = oLB[r];
    }
  }

  #pragma unroll
  for (int r = 0; r < 4; r++) {
    const long rowA = ((long)b * SEQ + qw0 + fq * 4 + r) * DIM + h * HD;
    const long rowB = rowA + 16L * DIM;
    #pragma unroll
    for (int jd = 0; jd < 4; jd++) {
      Op[rowA + jd * 16 + fm] = (bf16_t)oA[jd][r];
      Op[rowB + jd * 16 + fm] = (bf16_t)oB[jd][r];
    }
  }
}

// ------------------------------------------------------------------
// ws layout — 65 MB (unchanged):
// ------------------------------------------------------------------
extern "C" void kernel_launch(void* const* d_in, const int* in_sizes, int n_in,
                              void* d_out, int out_size, void* d_ws, size_t ws_size,
                              hipStream_t stream) {
  (void)in_sizes; (void)n_in; (void)out_size; (void)ws_size;
  const float* x      = (const float*)d_in[0];
  const float* wq     = (const float*)d_in[2];
  const float* wk     = (const float*)d_in[3];
  const float* wv     = (const float*)d_in[4];
  const float* wo     = (const float*)d_in[5];
  const float* w_up   = (const float*)d_in[6];
  const float* b_up   = (const float*)d_in[7];
  const float* w_down = (const float*)d_in[8];
  const float* b_down = (const float*)d_in[9];
  const float* ln1a   = (const float*)d_in[10];
  const float* ln1b   = (const float*)d_in[11];
  const float* ln2a   = (const float*)d_in[12];
  const float* ln2b   = (const float*)d_in[13];

  char* ws = (char*)d_ws;
  const size_t MB = 1ull << 20;
  const size_t KB = 1ull << 10;
  float*  l0     = (float*)(ws);              // 256 KB
  float*  l1     = (float*)(ws + 256 * KB);   // 256 KB
  bf16_t* wqkvT  = (bf16_t*)(ws + 512 * KB);  // 6 MB
  bf16_t* woT    = (bf16_t*)(ws + 512 * KB + 6 * MB);  // 2 MB
  bf16_t* h      = (bf16_t*)(ws + 9 * MB);
  bf16_t* O0     = (bf16_t*)(ws + 9 * MB);
  bf16_t* attn   = (bf16_t*)(ws + 9 * MB);
  bf16_t* qkv    = (bf16_t*)(ws + 17 * MB);
  bf16_t* qd     = (bf16_t*)(ws + 17 * MB);
  bf16_t* kd     = (bf16_t*)(ws + 25 * MB);
  bf16_t* vtd    = (bf16_t*)(ws + 33 * MB);
  bf16_t* O1     = (bf16_t*)(ws + 41 * MB);
  bf16_t* p0_wo  = (bf16_t*)(ws + 17 * MB);
  bf16_t* p1_wo  = (bf16_t*)(ws + 25 * MB);
  bf16_t* x1b    = (bf16_t*)(ws + 41 * MB);
  bf16_t* h2     = (bf16_t*)(ws);
  bf16_t* wdownT = (bf16_t*)(ws + 49 * MB);
  bf16_t* wupT   = (bf16_t*)(ws + 57 * MB);
  bf16_t* ff1    = (bf16_t*)(ws + 9 * MB);
  bf16_t* p0_fd  = (bf16_t*)(ws);
  bf16_t* p1_fd  = (bf16_t*)(ws + 57 * MB);
  float*  outp   = (float*)d_out;

  const dim3 T(256);
  TP tp{wq, wk, wv, wo, w_up, w_down, wqkvT, wupT, wdownT};
  transpose_all<<<dim3(12288), T, 0, stream>>>(tp);

  layernorm_k<<<dim3(4096), T, 0, stream>>>(x, ln1a, ln1b, h);
  gemm_bt<EPI_QKV, 128><<<dim3(24, 32), T, 0, stream>>>(h, DIM, wqkvT, DIM, qkv, vtd,
                                                        nullptr, NTOK, 3072, DIM);
  flash_attn<<<dim3(512, 2), T, 0, stream>>>(qd, kd, vtd, O0, O1, l0, l1);
  combine_att<<<dim3(NTOK * DIM / 1024), T, 0, stream>>>(O1, l0, l1, attn);
  gemm_bt<EPI_PART, 64><<<dim3(16, 32, 2), T, 0, stream>>>(attn, DIM, woT, DIM, p0_wo, p1_wo,
                                                           nullptr, NTOK, DIM, DIM / 2);
  reduce_wo_ln<<<dim3(4096), T, 0, stream>>>(x, p0_wo, p1_wo, ln2a, ln2b, x1b, h2);
  gemm_bt<EPI_BIAS_RELU, 128><<<dim3(32, 32), T, 0, stream>>>(h2, DIM, wupT, DIM, ff1, nullptr,
                                                              b_up, NTOK, DFF, DIM);
  gemm_bt<EPI_PART, 64><<<dim3(16, 32, 2), T, 0, stream>>>(ff1, DFF, wdownT, DFF, p0_fd, p1_fd,
                                                           nullptr, NTOK, DIM, DFF / 2);
  reduce_fd<<<dim3(NTOK * DIM / 1024), T, 0, stream>>>(x1b, b_down, p0_fd, p1_fd, outp);
}